// Round 4
// baseline (649.181 us; speedup 1.0000x reference)
//
#include <hip/hip_runtime.h>
#include <cstdint>
#include <cstddef>

// GCNClassifier: 2x AGNNConv(D=320) -> marker weight -> BN+LeakyReLU ->
// softmax @ ref_center -> 2x AGNNConv(D=16) -> row softmax.
// N=50000, E=300000 (incl. self-loops => every dst segment non-empty).
//
// R4: split conv into thread-per-edge score kernel (no cross-lane ops) +
// wave-per-node aggregate with in-register chunk softmax; inverse norms
// precomputed once per matrix (epilogue-fused where the row is in registers).

#define D_BIG 320

__device__ __forceinline__ float dot4(float4 a, float4 b) {
    return a.x * b.x + a.y * b.y + a.z * b.z + a.w * b.w;
}

__global__ void fill_u32(unsigned* p, unsigned v, int n) {
    int i = blockIdx.x * blockDim.x + threadIdx.x;
    if (i < n) p[i] = v;
}

// ---------------- CSR build (dst-major) ----------------
__global__ void count_deg(const int* __restrict__ dst, unsigned* __restrict__ deg, int nE) {
    int k = blockIdx.x * blockDim.x + threadIdx.x;
    if (k < nE) atomicAdd(&deg[dst[k]], 1u);
}

__global__ void scan1(const unsigned* __restrict__ deg, unsigned* __restrict__ rs,
                      unsigned* __restrict__ bsum, int n) {
    __shared__ unsigned buf[256];
    int i = blockIdx.x * 256 + threadIdx.x;
    unsigned v = (i < n) ? deg[i] : 0u;
    buf[threadIdx.x] = v;
    __syncthreads();
    for (int off = 1; off < 256; off <<= 1) {
        unsigned t = (threadIdx.x >= (unsigned)off) ? buf[threadIdx.x - off] : 0u;
        __syncthreads();
        buf[threadIdx.x] += t;
        __syncthreads();
    }
    if (i < n) rs[i] = buf[threadIdx.x] - v;           // exclusive
    if (threadIdx.x == 255) bsum[blockIdx.x] = buf[255];
}

__global__ void scan2(unsigned* __restrict__ bsum, int nb) {   // nb <= 256
    __shared__ unsigned buf[256];
    unsigned v = ((int)threadIdx.x < nb) ? bsum[threadIdx.x] : 0u;
    buf[threadIdx.x] = v;
    __syncthreads();
    for (int off = 1; off < 256; off <<= 1) {
        unsigned t = (threadIdx.x >= (unsigned)off) ? buf[threadIdx.x - off] : 0u;
        __syncthreads();
        buf[threadIdx.x] += t;
        __syncthreads();
    }
    if ((int)threadIdx.x < nb) bsum[threadIdx.x] = buf[threadIdx.x] - v;   // exclusive
}

__global__ void scan3(unsigned* __restrict__ rs, const unsigned* __restrict__ bsum,
                      unsigned* __restrict__ cursor, float* __restrict__ stats,
                      int n, int nE) {
    int i = blockIdx.x * 256 + threadIdx.x;
    if (i < n) { rs[i] += bsum[blockIdx.x]; cursor[i] = 0u; }
    if (i == 0) rs[n] = (unsigned)nE;
    if (blockIdx.x == 0 && threadIdx.x < 64) stats[threadIdx.x] = 0.f;
}

__global__ void scatter_edges(const int* __restrict__ src, const int* __restrict__ dst,
                              const unsigned* __restrict__ rowstart, unsigned* __restrict__ cursor,
                              int* __restrict__ esrc, int* __restrict__ edst, int nE) {
    int k = blockIdx.x * blockDim.x + threadIdx.x;
    if (k >= nE) return;
    int t = dst[k];
    unsigned pos = rowstart[t] + atomicAdd(&cursor[t], 1u);
    esrc[pos] = src[k];
    edst[pos] = t;
}

// ---------------- inverse row norms, D=320 (wave per node) ----------------
__global__ void norms_big(const float* __restrict__ h, float* __restrict__ rn, int n) {
    int i    = (blockIdx.x * blockDim.x + threadIdx.x) >> 6;
    int lane = threadIdx.x & 63;
    if (i >= n) return;
    const float4* pd = (const float4*)(h + (size_t)i * D_BIG);
    float4 d0 = pd[lane];
    float4 d1 = (lane < 16) ? pd[64 + lane] : float4{0.f, 0.f, 0.f, 0.f};
    float q = dot4(d0, d0) + dot4(d1, d1);
    #pragma unroll
    for (int m = 32; m >= 1; m >>= 1) q += __shfl_xor(q, m);
    if (lane == 0) rn[i] = 1.f / fmaxf(sqrtf(q), 1e-12f);
}

// ---------------- edge scores, thread per edge ----------------
__global__ void score_big(const float* __restrict__ h, const float* __restrict__ rn,
                          const int* __restrict__ esrc, const int* __restrict__ edst,
                          const float* __restrict__ beta, float* __restrict__ sco, int nE) {
    int j = blockIdx.x * blockDim.x + threadIdx.x;
    if (j >= nE) return;
    int s = esrc[j], t = edst[j];
    float b0 = beta[0];
    float sc;
    if (s == t) {
        sc = b0;                                   // cos(h,h) = 1, temp = 1
    } else {
        const float4* ps = (const float4*)(h + (size_t)s * D_BIG);
        const float4* pt = (const float4*)(h + (size_t)t * D_BIG);
        float d0 = 0.f, d1 = 0.f;
        #pragma unroll 4
        for (int k = 0; k < 80; k += 2) {
            d0 += dot4(ps[k], pt[k]);
            d1 += dot4(ps[k + 1], pt[k + 1]);
        }
        sc = b0 * (d0 + d1) * rn[s] * rn[t];
    }
    sco[j] = sc;
}

__global__ void score_small(const float* __restrict__ h, const float* __restrict__ rn,
                            const int* __restrict__ esrc, const int* __restrict__ edst,
                            const float* __restrict__ beta, float* __restrict__ sco, int nE) {
    int j = blockIdx.x * blockDim.x + threadIdx.x;
    if (j >= nE) return;
    int s = esrc[j], t = edst[j];
    float b0 = beta[0];
    float sc;
    if (s == t) {
        sc = b0;
    } else {
        const float4* ps = (const float4*)(h + (size_t)s * 16);
        const float4* pt = (const float4*)(h + (size_t)t * 16);
        float dot = 0.f;
        #pragma unroll
        for (int q = 0; q < 4; q++) dot += dot4(ps[q], pt[q]);
        sc = b0 * dot * rn[s] * rn[t];
    }
    sco[j] = sc;
}

// ---------------- aggregate D=320: wave per node, chunk softmax ------------
// EPI: 0 = store + invnorm epilogue (rn_out), 1 = marker-weight + f_pre
template <int EPI>
__global__ void agg_big(const float* __restrict__ h,
                        const unsigned* __restrict__ rowstart,
                        const int* __restrict__ esrc,
                        const float* __restrict__ sco,
                        const float* __restrict__ mw,      // EPI==1
                        float* __restrict__ out,
                        float* __restrict__ f_out,         // EPI==1
                        float* __restrict__ rn_out,        // EPI==0
                        int n) {
    int i    = (blockIdx.x * blockDim.x + threadIdx.x) >> 6;
    int lane = threadIdx.x & 63;
    if (i >= n) return;
    int l15 = lane & 15;
    bool lo = lane < 16;
    unsigned r0 = rowstart[i], r1 = rowstart[i + 1];

    float4 a0 = {0.f, 0.f, 0.f, 0.f}, a1 = {0.f, 0.f, 0.f, 0.f};
    float mrun = -3e38f, lrun = 0.f;

    for (unsigned base = r0; base < r1; base += 64) {
        unsigned j = base + (unsigned)lane;
        bool vld = j < r1;
        float sc = vld ? sco[j] : -3e38f;
        int   sv = vld ? esrc[j] : 0;
        // chunk max
        float cm = sc;
        #pragma unroll
        for (int m = 32; m >= 1; m >>= 1) cm = fmaxf(cm, __shfl_xor(cm, m));
        float mnew  = fmaxf(mrun, cm);
        float alpha = __expf(mrun - mnew);       // first chunk: exp(-inf) = 0
        float w     = __expf(sc - mnew);         // invalid lanes -> 0
        float S = w;
        #pragma unroll
        for (int m = 32; m >= 1; m >>= 1) S += __shfl_xor(S, m);
        lrun = lrun * alpha + S;
        mrun = mnew;
        a0.x *= alpha; a0.y *= alpha; a0.z *= alpha; a0.w *= alpha;
        a1.x *= alpha; a1.y *= alpha; a1.z *= alpha; a1.w *= alpha;

        int cnt = (int)min(r1 - base, 64u);
        for (int t = 0; t < cnt; t++) {
            int   s  = __shfl(sv, t);
            float wt = __shfl(w, t);
            const float4* ps = (const float4*)(h + (size_t)s * D_BIG);
            float4 rv0 = ps[lane];
            float4 rv1 = ps[64 + l15];           // duplicate-addr on lanes>=16 (HW-merged)
            a0.x = fmaf(wt, rv0.x, a0.x); a0.y = fmaf(wt, rv0.y, a0.y);
            a0.z = fmaf(wt, rv0.z, a0.z); a0.w = fmaf(wt, rv0.w, a0.w);
            a1.x = fmaf(wt, rv1.x, a1.x); a1.y = fmaf(wt, rv1.y, a1.y);
            a1.z = fmaf(wt, rv1.z, a1.z); a1.w = fmaf(wt, rv1.w, a1.w);
        }
    }
    float inv = 1.f / lrun;
    a0.x *= inv; a0.y *= inv; a0.z *= inv; a0.w *= inv;
    a1.x *= inv; a1.y *= inv; a1.z *= inv; a1.w *= inv;

    float4* po = (float4*)(out + (size_t)i * D_BIG);
    if (EPI == 0) {
        po[lane] = a0;
        if (lo) po[64 + lane] = a1;
        float q = dot4(a0, a0) + (lo ? dot4(a1, a1) : 0.f);
        #pragma unroll
        for (int m = 32; m >= 1; m >>= 1) q += __shfl_xor(q, m);
        if (lane == 0) rn_out[i] = 1.f / fmaxf(sqrtf(q), 1e-12f);
    } else {
        const float4* pmw = (const float4*)mw;
        float4 w0 = pmw[lane];
        float4 w1 = pmw[64 + l15];
        float4 v0 = {a0.x * w0.x, a0.y * w0.y, a0.z * w0.z, a0.w * w0.w};
        float4 v1 = {a1.x * w1.x, a1.y * w1.y, a1.z * w1.z, a1.w * w1.w};
        po[lane] = v0;
        if (lo) po[64 + lane] = v1;
        float4 v1m = lo ? v1 : float4{0.f, 0.f, 0.f, 0.f};
        // f_pre: channel c = (4*lane+q)&15 for both halves -> xor-reduce 4..32
        float fs[4] = {v0.x + v1m.x, v0.y + v1m.y, v0.z + v1m.z, v0.w + v1m.w};
        #pragma unroll
        for (int mask = 4; mask <= 32; mask <<= 1) {
            #pragma unroll
            for (int q = 0; q < 4; q++) fs[q] += __shfl_xor(fs[q], mask);
        }
        if (lane < 4) {
            float4* pf = (float4*)(f_out + (size_t)i * 16);
            pf[lane] = float4{fs[0], fs[1], fs[2], fs[3]};
        }
    }
}

// ---------------- aggregate D=16: wave per node ----------------
// EPI: 0 = store + invnorm epilogue, 2 = row softmax(val * inv_temp)
template <int EPI>
__global__ void agg_small(const float* __restrict__ h,
                          const unsigned* __restrict__ rowstart,
                          const int* __restrict__ esrc,
                          const float* __restrict__ sco,
                          float* __restrict__ out,
                          float* __restrict__ rn_out,      // EPI==0
                          float inv_temp,                  // EPI==2
                          int n) {
    int i    = (blockIdx.x * blockDim.x + threadIdx.x) >> 6;
    int lane = threadIdx.x & 63;
    if (i >= n) return;
    int l15 = lane & 15;
    unsigned r0 = rowstart[i], r1 = rowstart[i + 1];

    float acc = 0.f, mrun = -3e38f, lrun = 0.f;
    for (unsigned base = r0; base < r1; base += 64) {
        unsigned j = base + (unsigned)lane;
        bool vld = j < r1;
        float sc = vld ? sco[j] : -3e38f;
        int   sv = vld ? esrc[j] : 0;
        float cm = sc;
        #pragma unroll
        for (int m = 32; m >= 1; m >>= 1) cm = fmaxf(cm, __shfl_xor(cm, m));
        float mnew  = fmaxf(mrun, cm);
        float alpha = __expf(mrun - mnew);
        float w     = __expf(sc - mnew);
        float S = w;
        #pragma unroll
        for (int m = 32; m >= 1; m >>= 1) S += __shfl_xor(S, m);
        lrun = lrun * alpha + S;
        mrun = mnew;
        acc *= alpha;

        int cnt = (int)min(r1 - base, 64u);
        for (int t = 0; t < cnt; t++) {
            int   s  = __shfl(sv, t);
            float wt = __shfl(w, t);
            float rv = h[(size_t)s * 16 + l15];  // duplicate-addr on lanes>=16
            acc = fmaf(wt, rv, acc);
        }
    }
    float val = acc / lrun;

    if (EPI == 0) {
        if (lane < 16) out[(size_t)i * 16 + lane] = val;
        float q = val * val;                      // lanes>=16 duplicate l15's val
        #pragma unroll
        for (int m = 8; m >= 1; m >>= 1) q += __shfl_xor(q, m);  // within 16-group
        if (lane == 0) rn_out[i] = 1.f / fmaxf(sqrtf(q), 1e-12f);
    } else {
        float v = val * inv_temp;
        float m2 = v;
        #pragma unroll
        for (int mm = 8; mm >= 1; mm >>= 1) m2 = fmaxf(m2, __shfl_xor(m2, mm));
        float ee = __expf(v - m2);
        float ssum = ee;
        #pragma unroll
        for (int mm = 8; mm >= 1; mm >>= 1) ssum += __shfl_xor(ssum, mm);
        if (lane < 16) out[(size_t)i * 16 + lane] = ee / ssum;
    }
}

// ---------------- BatchNorm stats ----------------
__global__ void bn_reduce(const float* __restrict__ f, float* __restrict__ stats, int n) {
    int c = threadIdx.x & 15;
    int g = threadIdx.x >> 4;
    float s = 0.f, s2 = 0.f;
    for (int i = blockIdx.x * 16 + g; i < n; i += gridDim.x * 16) {
        float v = f[(size_t)i * 16 + c];
        s += v; s2 += v * v;
    }
    __shared__ float ls[256], ls2[256];
    ls[threadIdx.x] = s; ls2[threadIdx.x] = s2;
    __syncthreads();
    for (int off = 128; off >= 16; off >>= 1) {
        if ((int)threadIdx.x < off) {
            ls[threadIdx.x]  += ls[threadIdx.x + off];
            ls2[threadIdx.x] += ls2[threadIdx.x + off];
        }
        __syncthreads();
    }
    if (threadIdx.x < 16) {
        atomicAdd(&stats[threadIdx.x], ls[threadIdx.x]);
        atomicAdd(&stats[16 + threadIdx.x], ls2[threadIdx.x]);
    }
}

__global__ void bn_finalize(float* __restrict__ stats, const float* __restrict__ w,
                            const float* __restrict__ b, int n) {
    int c = threadIdx.x;
    if (c < 16) {
        float mean  = stats[c] / (float)n;
        float var   = fmaxf(stats[16 + c] / (float)n - mean * mean, 0.f);
        float scale = w[c] / sqrtf(var + 1e-5f);
        stats[32 + c] = scale;
        stats[48 + c] = b[c] - mean * scale;
    }
}

// ------ BN apply + LeakyReLU + softmax(f*10) @ ref_center + invnorm(f) ------
__global__ void bn_apply_p(float* __restrict__ f, const float* __restrict__ stats,
                           const float* __restrict__ rc, float* __restrict__ p,
                           float* __restrict__ rn_out, int n) {
    __shared__ float s_rc[16 * D_BIG];   // 20 KB
    __shared__ float s_sc[16], s_sh[16];
    for (int idx = threadIdx.x; idx < 16 * D_BIG; idx += blockDim.x) s_rc[idx] = rc[idx];
    if (threadIdx.x < 16) { s_sc[threadIdx.x] = stats[32 + threadIdx.x]; s_sh[threadIdx.x] = stats[48 + threadIdx.x]; }
    __syncthreads();

    int wave = (blockIdx.x * blockDim.x + threadIdx.x) >> 6;
    int nw   = (gridDim.x * blockDim.x) >> 6;
    int lane = threadIdx.x & 63;

    for (int i = wave; i < n; i += nw) {
        const float* fr = f + (size_t)i * 16;
        float fv[16];
        float mx = -1e30f, q = 0.f;
        #pragma unroll
        for (int c = 0; c < 16; c++) {
            float v = fmaf(fr[c], s_sc[c], s_sh[c]);
            v = (v >= 0.f) ? v : 0.25f * v;           // LeakyReLU(0.25)
            fv[c] = v;
            mx = fmaxf(mx, v);
            q = fmaf(v, v, q);
        }
        if (lane < 16) f[(size_t)i * 16 + lane] = fv[lane];   // lockstep: loads precede stores
        if (lane == 0) rn_out[i] = 1.f / fmaxf(sqrtf(q), 1e-12f);

        float sp[16]; float sum = 0.f;
        #pragma unroll
        for (int c = 0; c < 16; c++) { float t = __expf((fv[c] - mx) * 10.0f); sp[c] = t; sum += t; }
        float isum = 1.f / sum;

        #pragma unroll
        for (int u = 0; u < 5; u++) {
            int d = lane + 64 * u;
            float acc = 0.f;
            #pragma unroll
            for (int c = 0; c < 16; c++) acc += sp[c] * s_rc[c * D_BIG + d];
            p[(size_t)i * D_BIG + d] = acc * isum;
        }
    }
}

extern "C" void kernel_launch(void* const* d_in, const int* in_sizes, int n_in,
                              void* d_out, int out_size, void* d_ws, size_t ws_size,
                              hipStream_t stream) {
    const float* x    = (const float*)d_in[0];
    const int*   src  = (const int*)d_in[1];
    const int*   dst  = (const int*)d_in[2];
    const float* mw   = (const float*)d_in[3];
    const float* bnw  = (const float*)d_in[4];
    const float* bnb  = (const float*)d_in[5];
    const float* rc   = (const float*)d_in[6];
    const float* beta = (const float*)d_in[7];

    const int n  = in_sizes[0] / D_BIG;   // 50000
    const int nE = in_sizes[1];           // 300000

    float* out     = (float*)d_out;
    float* fea_out = out;                          // N*320
    float* f_out   = out + (size_t)n * D_BIG;      // N*16
    float* p_out   = f_out + (size_t)n * 16;       // N*320
    float* o_out   = p_out + (size_t)n * D_BIG;    // N*16

    // workspace carve (~8 MB)
    char* w = (char*)d_ws;
    auto carve = [&](size_t bytes) { void* r = (void*)w; w += (bytes + 255) & ~(size_t)255; return r; };
    unsigned* deg      = (unsigned*)carve((size_t)n * 4);
    unsigned* rowstart = (unsigned*)carve((size_t)(n + 1) * 4);
    unsigned* cursor   = (unsigned*)carve((size_t)n * 4);
    unsigned* bsum     = (unsigned*)carve(256 * 4);
    int*      esrc     = (int*)carve((size_t)nE * 4);
    int*      edst     = (int*)carve((size_t)nE * 4);
    float*    sco      = (float*)carve((size_t)nE * 4);
    float*    rn       = (float*)carve((size_t)n * 4);   // reused across stages
    float*    stats    = (float*)carve(64 * 4);
    float*    t16      = (float*)carve((size_t)n * 16 * 4);
    float*    h1       = p_out;  // p region doubles as conv1 output until bn_apply_p

    const int TB = 256;
    auto cdiv = [](int a, int b) { return (a + b - 1) / b; };
    const int nb = cdiv(n, 256);   // 196 (<=256 required by scan2)

    // CSR build (once; reused by all 4 convs)
    fill_u32<<<cdiv(n, TB), TB, 0, stream>>>(deg, 0u, n);
    count_deg<<<cdiv(nE, TB), TB, 0, stream>>>(dst, deg, nE);
    scan1<<<nb, 256, 0, stream>>>(deg, rowstart, bsum, n);
    scan2<<<1, 256, 0, stream>>>(bsum, nb);
    scan3<<<nb, 256, 0, stream>>>(rowstart, bsum, cursor, stats, n, nE);
    scatter_edges<<<cdiv(nE, TB), TB, 0, stream>>>(src, dst, rowstart, cursor, esrc, edst, nE);

    // conv1: x -> h1 (p region); rn(x) standalone, rn(h1) from epilogue
    norms_big<<<cdiv(n, 4), TB, 0, stream>>>(x, rn, n);
    score_big<<<cdiv(nE, TB), TB, 0, stream>>>(x, rn, esrc, edst, beta, sco, nE);
    agg_big<0><<<cdiv(n, 4), TB, 0, stream>>>(x, rowstart, esrc, sco, nullptr,
                                              h1, nullptr, rn, n);
    // conv2 + marker + f_pre: h1 -> fea_out, f_out
    score_big<<<cdiv(nE, TB), TB, 0, stream>>>(h1, rn, esrc, edst, beta, sco, nE);
    agg_big<1><<<cdiv(n, 4), TB, 0, stream>>>(h1, rowstart, esrc, sco, mw,
                                              fea_out, f_out, nullptr, n);
    // BatchNorm (training-mode batch stats)
    bn_reduce<<<128, TB, 0, stream>>>(f_out, stats, n);
    bn_finalize<<<1, 16, 0, stream>>>(stats, bnw, bnb, n);
    // BN apply + LeakyReLU (f in place) + p = softmax(f*10) @ rc; rn(f) epilogue
    bn_apply_p<<<512, TB, 0, stream>>>(f_out, stats, rc, p_out, rn, n);
    // conv3: f -> t16; rn(t16) from epilogue
    score_small<<<cdiv(nE, TB), TB, 0, stream>>>(f_out, rn, esrc, edst, beta, sco, nE);
    agg_small<0><<<cdiv(n, 4), TB, 0, stream>>>(f_out, rowstart, esrc, sco, t16, rn, 0.f, n);
    // conv4 + softmax(/T2): t16 -> o_out
    score_small<<<cdiv(nE, TB), TB, 0, stream>>>(t16, rn, esrc, edst, beta, sco, nE);
    agg_small<2><<<cdiv(n, 4), TB, 0, stream>>>(t16, rowstart, esrc, sco, o_out, nullptr, 0.2f, n);
}